// Round 5
// baseline (383.878 us; speedup 1.0000x reference)
//
#include <hip/hip_runtime.h>
#include <cstdint>
#include <cstddef>

// ---------------- problem constants (fixed by setup_inputs) ----------------
static constexpr int D_IN = 784;
static constexpr int H1   = 2048;
static constexpr int H2   = 10;
static constexpr int KK   = 10;
static constexpr int UU   = 2832;   // D_IN + H1
static constexpr int LL   = 128;
static constexpr int BB   = 1024;
static constexpr int TT   = 20;
static constexpr int HALF = BB * D_IN / 2;   // 401408 = 512*784
static constexpr int NCH  = 25;              // K chunks of 32 (784 -> 800 padded)
static constexpr int NLIMB = 3;              // signed base-256 limbs of round(W1*2^24)
static constexpr int XA_T  = 32 * NCH * 64;  // v4i per time-step of spike fragments
static constexpr int BITS_T = BB * 64;       // uint32 per time-step of h1s bitmask
static constexpr int PANEL = NCH * NLIMB * 64;  // v4i per ntile B-panel (4800)
static constexpr int NPART = 256;            // h1_all partial slots

// prep mega-kernel block ranges (vals + w2t + limbs + gen all in ONE launch;
// gen no longer depends on v1/v2 — x-side sums go through integer xcnt[k])
static constexpr int BLK_VALS  = (KK * UU) / 4;          // 7080
static constexpr int BLK_W2T   = H1 / 256;               // 8
static constexpr int BLK_LIMBS = (64 * NCH * 64) / 256;  // 400
static constexpr int BLK_GEN   = TT * 100;               // 2000
static constexpr int PREP_BLOCKS = BLK_VALS + BLK_W2T + BLK_LIMBS + BLK_GEN;

typedef int v4i  __attribute__((ext_vector_type(4)));
typedef int v16i __attribute__((ext_vector_type(16)));

#define MFMA_I8 __builtin_amdgcn_mfma_i32_32x32x32_i8

// ---------------- JAX threefry2x32 (20 rounds), bit-exact ----------------
__device__ __forceinline__ uint32_t rotl32(uint32_t x, int d) {
  return (x << d) | (x >> (32 - d));
}
__device__ __forceinline__ void threefry2x32(uint32_t k0, uint32_t k1,
                                             uint32_t& x0, uint32_t& x1) {
  uint32_t ks2 = k0 ^ k1 ^ 0x1BD11BDAu;
  x0 += k0; x1 += k1;
#define TF_R(r) { x0 += x1; x1 = rotl32(x1, (r)); x1 ^= x0; }
  TF_R(13) TF_R(15) TF_R(26) TF_R(6)
  x0 += k1;  x1 += ks2 + 1u;
  TF_R(17) TF_R(29) TF_R(16) TF_R(24)
  x0 += ks2; x1 += k0 + 2u;
  TF_R(13) TF_R(15) TF_R(26) TF_R(6)
  x0 += k0;  x1 += k1 + 3u;
  TF_R(17) TF_R(29) TF_R(16) TF_R(24)
  x0 += k1;  x1 += ks2 + 4u;
  TF_R(13) TF_R(15) TF_R(26) TF_R(6)
  x0 += ks2; x1 += k0 + 5u;
#undef TF_R
}
__device__ __forceinline__ float bits_to_unif(uint32_t b) {
  uint32_t fb = (b >> 9) | 0x3F800000u;
  return __uint_as_float(fb) - 1.0f;
}

// ---------------- block-wide 3-way fp64 reduction -> per-block partial slot ----
__device__ __forceinline__ double wave_red(double v) {
  #pragma unroll
  for (int off = 32; off > 0; off >>= 1) v += __shfl_down(v, off, 64);
  return v;
}
__device__ __forceinline__ void block_store3(double s0, double s1, double s2,
                                             double* slot) {
  __shared__ double lds[3][8];
  int lane = threadIdx.x & 63, w = threadIdx.x >> 6;
  int nw = (int)(blockDim.x >> 6);
  s0 = wave_red(s0); s1 = wave_red(s1); s2 = wave_red(s2);
  if (lane == 0) { lds[0][w] = s0; lds[1][w] = s1; lds[2][w] = s2; }
  __syncthreads();
  if (threadIdx.x == 0) {
    double t0 = 0, t1 = 0, t2 = 0;
    for (int i = 0; i < nw; i++) { t0 += lds[0][i]; t1 += lds[1][i]; t2 += lds[2][i]; }
    slot[0] = t0; slot[1] = t1; slot[2] = t2;
  }
}

// ---------------- prep: vals + W2T + limbs + spike-gen, ONE launch ------------
__global__ __launch_bounds__(256)
void prep(const float* __restrict__ cmv, const int* __restrict__ cmc,
          float* __restrict__ v1, float* __restrict__ v2,
          const float* __restrict__ W2, float* __restrict__ W2T,
          const float* __restrict__ W1, v4i* __restrict__ W1L,
          const float* __restrict__ input, v4i* __restrict__ XA,
          int* __restrict__ xcnt) {
  int bx = blockIdx.x;
  if (bx < BLK_VALS) {
    // ---- val1/val2: one wave per (k,u), ballot for last nonzero ----
    int gw = (bx * 256 + threadIdx.x) >> 6;
    int lane = threadIdx.x & 63;
    const float* p = cmv + (size_t)gw * LL;
    float a = p[lane];
    float b = p[lane + 64];
    unsigned long long mlo = __ballot(a != 0.0f);
    unsigned long long mhi = __ballot(b != 0.0f);
    if (lane == 0) {
      int u = gw % UU;
      int c = cmc[gw];
      int last = mhi ? (127 - __builtin_clzll(mhi))
                     : (mlo ? (63 - __builtin_clzll(mlo)) : -1);
      if (c > 0) {
        if (last >= 0) atomicAdd(&v1[u], (float)(last - 1));   // spread addresses
        atomicAdd(&v2[u], (float)c);
      }
    }
  } else if (bx < BLK_VALS + BLK_W2T) {
    // ---- W2T[i][j] = W2[j][i] ----
    int i = (bx - BLK_VALS) * 256 + threadIdx.x;
    #pragma unroll
    for (int j = 0; j < H2; j++) W2T[i * H2 + j] = W2[j * H1 + i];
  } else if (bx < BLK_VALS + BLK_W2T + BLK_LIMBS) {
    // ---- W1 -> 3 signed base-256 int8 limbs of round(W1*2^24), B-frag order ----
    // W1L index: ((ntile*NCH + chunk)*NLIMB + limb)*64 + lane
    // lane map: n = ntile*32 + (lane&31), k = chunk*32 + (lane>>5)*16 + j
    int tid = (bx - BLK_VALS - BLK_W2T) * 256 + threadIdx.x;
    int lane = tid & 63;
    int tc = tid >> 6;                           // ntile*NCH + chunk
    int n = ((tc / NCH) << 5) + (lane & 31);
    int chunk = tc % NCH;
    int k0 = chunk * 32 + (lane >> 5) * 16;
    union { v4i v; signed char b[16]; } d[NLIMB];
    #pragma unroll
    for (int j = 0; j < 16; j++) {
      long long F = 0;
      int k = k0 + j;
      if (k < D_IN) {
        double w = (double)W1[(size_t)n * D_IN + k];
        F = llround(w * 0x1p24);
        if (F >  8355711LL) F =  8355711LL;
        if (F < -8421504LL) F = -8421504LL;
      }
      #pragma unroll
      for (int l = 0; l < NLIMB; l++) {
        int dig = (int)((F + 128) & 255) - 128;
        d[l].b[j] = (signed char)dig;
        F = (F - dig) >> 8;
      }
    }
    #pragma unroll
    for (int l = 0; l < NLIMB; l++) W1L[(size_t)(tc * NLIMB + l) * 64 + lane] = d[l].v;
  } else {
    // ---- spike generation, A-fragment order + integer column counts ----
    // XA_t index: (mtile*NCH + chunk)*64 + lane
    // lane map: m = mtile*32 + (lane&31), k = chunk*32 + (lane>>5)*16 + j
    int gb = bx - (BLK_VALS + BLK_W2T + BLK_LIMBS);
    int t  = gb / 100;
    int gw = (gb % 100) * 4 + (threadIdx.x >> 6);
    int lane = threadIdx.x & 63;
    int mtile = gw / NCH, chunk = gw - mtile * NCH;  // mtile in [0,16): m < 512
    int m = (mtile << 5) + (lane & 31);
    int k0 = chunk * 32 + (lane >> 5) * 16;
    uint32_t f0 = 0u, f1 = (uint32_t)t;
    threefry2x32(0u, 42u, f0, f1);
    union { v4i v; unsigned char b[16]; } r0, r1;
    v4i* XA_t = XA + (size_t)t * XA_T;
    if (k0 < D_IN) {  // whole 16-group valid (784=24*32+16: only chunk24/hi invalid)
      const float4* I0 = (const float4*)(input + (size_t)m * D_IN + k0);
      const float4* I1 = (const float4*)(input + (size_t)(m + 512) * D_IN + k0);
      float i0v[16], i1v[16];
      #pragma unroll
      for (int q = 0; q < 4; q++) {
        float4 a = I0[q], b4 = I1[q];
        i0v[q * 4 + 0] = a.x;  i0v[q * 4 + 1] = a.y;
        i0v[q * 4 + 2] = a.z;  i0v[q * 4 + 3] = a.w;
        i1v[q * 4 + 0] = b4.x; i1v[q * 4 + 1] = b4.y;
        i1v[q * 4 + 2] = b4.z; i1v[q * 4 + 3] = b4.w;
      }
      int cnt[16];
      #pragma unroll
      for (int j = 0; j < 16; j++) {
        int k = k0 + j;
        uint32_t c0 = (uint32_t)(m * D_IN + k), c1 = c0 + (uint32_t)HALF;
        threefry2x32(f0, f1, c0, c1);
        float u0 = bits_to_unif(c0), u1 = bits_to_unif(c1);
        unsigned char x0 = (i0v[j] > u0) ? 1 : 0;
        unsigned char x1 = (i1v[j] > u1) ? 1 : 0;
        r0.b[j] = x0; r1.b[j] = x1;
        // ballot bit L <-> lane L <-> (m-half = L&31 row, k-half = L>>5)
        unsigned long long b0 = __ballot(x0 != 0);
        unsigned long long b1 = __ballot(x1 != 0);
        cnt[j] = (lane < 32)
               ? (__popc((uint32_t)b0) + __popc((uint32_t)b1))
               : (__popc((uint32_t)(b0 >> 32)) + __popc((uint32_t)(b1 >> 32)));
      }
      if ((lane & 31) == 0) {   // lane 0 covers k0..k0+15 lo-half; lane 32 hi-half
        #pragma unroll
        for (int j = 0; j < 16; j++) atomicAdd(&xcnt[k0 + j], cnt[j]);
      }
    } else {
      r0.v = (v4i){0, 0, 0, 0};
      r1.v = (v4i){0, 0, 0, 0};
    }
    XA_t[(size_t)(mtile * NCH + chunk) * 64 + lane] = r0.v;
    XA_t[(size_t)((mtile + 16) * NCH + chunk) * 64 + lane] = r1.v;  // m+512 partner
  }
}

// ---------------- h1: ALL 20 steps, membrane in regs, t-pair blocked -----------
// 512-thread blocks (8 waves = 2 waves/SIMD; LDS rounds to 128 KB so 1 block/CU
// — round-2 lesson). All 8 waves share ONE ntile B-panel in LDS (staged once,
// reused 20x); wave wv owns one mtile. XCD swizzle: dispatch id%8 = XCD, each
// XCD pinned to one mt-group so its L2 holds only 1/4 of XA (round-4: FETCH
// 66->26 MB). K-loop FULLY unrolled with direct indexing — no hand rotation
// (round-4 VALUBusy showed ~24k cyc of register moves) — compiler emits counted
// lgkmcnt/vmcnt pipelining. s_setprio(1) across the MFMA-dense K-pass,
// setprio(0) in the store/VALU epilogue (waves have no intra-loop barrier ->
// desync -> T5 applies as in the attn case). Epilogue: exact int32 limb
// combine (mod-2^32 wraparound), f32 membrane chain.
__global__ __launch_bounds__(512, 2)
void h1_all(const v4i* __restrict__ XA, const v4i* __restrict__ W1L,
            const float* __restrict__ b1, uint32_t* __restrict__ bits,
            const float* __restrict__ v1, const float* __restrict__ v2,
            double* __restrict__ gpart) {
  extern __shared__ v4i bl[];                    // PANEL = 4800 v4i = 76800 B
  int lane = threadIdx.x & 63, wv = threadIdx.x >> 6;
  int id = blockIdx.x + (blockIdx.y << 6);       // dispatch-linear 0..255
  int xcd = id & 7;
  int idx = id >> 3;                             // 0..31
  int ntile = (idx << 1) | (xcd >> 2);           // 0..63
  int mtg = xcd & 3;                             // mt-group 0..3 (per-XCD fixed)
  int mt = mtg * 8 + wv;                         // [0,32)
  {
    const v4i* wp = W1L + (size_t)ntile * PANEL;
    for (int i = threadIdx.x; i < PANEL; i += 512) bl[i] = wp[i];
  }
  __syncthreads();

  int col = lane & 31;
  int gn = (ntile << 5) + col;
  float bias = b1[gn];
  double v1n = (double)v1[D_IN + gn], v2n = (double)v2[D_IN + gn];
  int scnt = 0;
  float mreg[16];
  #pragma unroll
  for (int r = 0; r < 16; r++) mreg[r] = 0.0f;

  const v4i* bq = bl + lane;
  #pragma unroll 1
  for (int tp = 0; tp < TT / 2; tp++) {
    const v4i* a0 = XA + (size_t)(2 * tp) * XA_T + (size_t)mt * (NCH * 64) + lane;
    const v4i* a1 = a0 + XA_T;
    v16i c00 = {}, c01 = {}, c02 = {};           // t = 2tp,   limbs 0..2
    v16i c10 = {}, c11 = {}, c12 = {};           // t = 2tp+1, limbs 0..2
    __builtin_amdgcn_s_setprio(1);
    #pragma unroll
    for (int c = 0; c < NCH; c++) {
      v4i A0 = a0[c * 64], A1 = a1[c * 64];
      const v4i* br = bq + (size_t)c * (NLIMB * 64);
      v4i B0 = br[0], B1 = br[64], B2 = br[128];
      c00 = MFMA_I8(A0, B0, c00, 0, 0, 0);
      c10 = MFMA_I8(A1, B0, c10, 0, 0, 0);
      c01 = MFMA_I8(A0, B1, c01, 0, 0, 0);
      c11 = MFMA_I8(A1, B1, c11, 0, 0, 0);
      c02 = MFMA_I8(A0, B2, c02, 0, 0, 0);
      c12 = MFMA_I8(A1, B2, c12, 0, 0, 0);
    }
    __builtin_amdgcn_s_setprio(0);
    // epilogue: t = 2tp then 2tp+1 (membrane chain order preserved)
    // C/D layout (32x32): col=lane&31, row=(r&3)+8*(r>>2)+4*(lane>>5)
    #pragma unroll
    for (int half = 0; half < 2; half++) {
      const v16i& q0 = half ? c10 : c00;
      const v16i& q1 = half ? c11 : c01;
      const v16i& q2 = half ? c12 : c02;
      uint32_t* btm = bits + (size_t)(2 * tp + half) * BITS_T
                    + ((size_t)mt << 5) * 64 + ntile;
      #pragma unroll
      for (int r = 0; r < 16; r++) {
        // exact: true val fits int31, so mod-2^32 wraparound combine is exact
        int val = (int)((uint32_t)q0[r] + ((uint32_t)q1[r] << 8)
                        + ((uint32_t)q2[r] << 16));
        float dot = (float)val * 0x1p-24f + bias;
        float mp = mreg[r];
        float mnew = (mp > 0.5f) ? dot : fmaf(mp, 0.2f, dot);
        bool s = (mnew > 0.5f);
        mreg[r] = mnew;
        unsigned long long bm = __ballot(s);
        int rowA = (r & 3) + 8 * (r >> 2);
        if ((lane & 31) == 0)
          btm[(size_t)(rowA + ((lane >> 5) << 2)) * 64] = (uint32_t)(bm >> (lane & 32));
        scnt += s ? 1 : 0;
      }
    }
  }
  double sc = (double)scnt;
  block_store3(sc * v1n, sc * v2n, sc, gpart + 3 * (size_t)id);
}

// ---------------- h2: ALL 20 steps, W2 slices in registers, 2 rows/block -------
// block = 4 waves; wave wq covers n in [wq*512,(wq+1)*512) for both rows
// (8 n-words per lane, weights register-resident); cross-wave combine via LDS;
// waves 0,1 advance the h2 chain for rows b0+0, b0+1 in lanes 0..9.
// Block 0 additionally reduces h1 partials + the exact x-side xcnt dot.
__global__ __launch_bounds__(256)
void h2_all(const uint32_t* __restrict__ bits, const float* __restrict__ W2T,
            const float* __restrict__ b2, const double* __restrict__ gpart,
            const int* __restrict__ xcnt, const float* __restrict__ v1,
            const float* __restrict__ v2, float* __restrict__ out) {
  int lane = threadIdx.x & 63, wq = threadIdx.x >> 6;
  int b0 = blockIdx.x * 2;
  float w[8][10];
  #pragma unroll
  for (int c = 0; c < 8; c++) {
    int n = (wq << 9) + (c << 6) + lane;         // n = wq*512 + c*64 + lane
    #pragma unroll
    for (int j = 0; j < 10; j++) w[c][j] = W2T[(size_t)n * H2 + j];
  }
  float m = 0.0f, sp = 0.0f, sm = 0.0f;
  float b2v = (lane < 10) ? b2[lane] : 0.0f;
  __shared__ float part[4][2][10];               // [wq][row][j]
  #pragma unroll 1
  for (int t = 0; t < TT; t++) {
    const uint32_t* bt = bits + (size_t)t * BITS_T;
    #pragma unroll
    for (int r = 0; r < 2; r++) {
      // lane L holds mask word (wq*16 + (L&15)) of row b0+r
      uint32_t myw = bt[(size_t)(b0 + r) * 64 + (wq << 4) + (lane & 15)];
      float p[10];
      #pragma unroll
      for (int j = 0; j < 10; j++) p[j] = 0.0f;
      #pragma unroll
      for (int c = 0; c < 8; c++) {
        // word for n = wq*512+c*64+lane lives at source lane 2c+(lane>>5)
        uint32_t wd = __shfl(myw, (c << 1) + (lane >> 5), 64);
        float f = (float)((wd >> (lane & 31)) & 1u);
        #pragma unroll
        for (int j = 0; j < 10; j++) p[j] += f * w[c][j];
      }
      #pragma unroll
      for (int j = 0; j < 10; j++) {
        float v = p[j];
        #pragma unroll
        for (int off = 32; off > 0; off >>= 1) v += __shfl_xor(v, off, 64);
        p[j] = v;
      }
      if (lane == 0) {
        #pragma unroll
        for (int j = 0; j < 10; j++) part[wq][r][j] = p[j];
      }
    }
    __syncthreads();
    if (wq < 2 && lane < 10) {
      float red = part[0][wq][lane] + part[1][wq][lane]
                + part[2][wq][lane] + part[3][wq][lane];
      m = m * 0.2f * (1.0f - sp) + red + b2v;
      sp = (m > 0.5f) ? 1.0f : 0.0f;
      sm += sp;
    }
    __syncthreads();
  }
  if (wq < 2 && lane < 10)
    out[(size_t)(b0 + wq) * H2 + lane] = (float)((double)sm / (double)TT);

  if (blockIdx.x == 0) {
    // final reduction: h1 per-block partials + exact integer x-side dot
    double t0 = 0, t1 = 0, t2 = 0;
    for (int i = threadIdx.x; i < NPART; i += 256) {
      t0 += gpart[3 * (size_t)i];
      t1 += gpart[3 * (size_t)i + 1];
      t2 += gpart[3 * (size_t)i + 2];
    }
    for (int k = threadIdx.x; k < D_IN; k += 256) {
      double c = (double)xcnt[k];
      t0 += c * (double)v1[k];
      t1 += c * (double)v2[k];
      t2 += c;
    }
    __shared__ double fin[3][4];
    t0 = wave_red(t0); t1 = wave_red(t1); t2 = wave_red(t2);
    if (lane == 0) { fin[0][wq] = t0; fin[1][wq] = t1; fin[2][wq] = t2; }
    __syncthreads();
    if (threadIdx.x == 0) {
      double a = 0, b = 0, cc = 0;
      #pragma unroll
      for (int i = 0; i < 4; i++) { a += fin[0][i]; b += fin[1][i]; cc += fin[2][i]; }
      out[(size_t)BB * H2 + 0] = (float)a;
      out[(size_t)BB * H2 + 1] = (float)b;
      out[(size_t)BB * H2 + 2] = (float)cc;
    }
  }
}

// ---------------- launch ----------------
extern "C" void kernel_launch(void* const* d_in, const int* in_sizes, int n_in,
                              void* d_out, int out_size, void* d_ws, size_t ws_size,
                              hipStream_t stream) {
  (void)in_sizes; (void)n_in; (void)out_size; (void)ws_size;
  const float* input = (const float*)d_in[0];
  const float* W1    = (const float*)d_in[1];
  const float* b1    = (const float*)d_in[2];
  const float* W2    = (const float*)d_in[3];
  const float* b2    = (const float*)d_in[4];
  const float* cmv   = (const float*)d_in[5];
  const int*   cmc   = (const int*)d_in[6];

  char* base = (char*)d_ws;
  // zeroed region (accumulators)
  float*  v1   = (float*)(base + 0);             //     11,328 B
  float*  v2   = (float*)(base + 11328);         //     11,328 B
  int*    xcnt = (int*)(base + 22656);           //      3,200 B (800 ints)
  const size_t ZERO_BYTES = 25856;
  // non-zeroed region (fully written before read)
  float*  W2T  = (float*)(base + 25856);         //     81,920 B
  v4i*    W1L  = (v4i*)(base + 107776);          //  4,915,200 B
  v4i*    XA   = (v4i*)(base + 5022976);         // 16,384,000 B
  uint32_t* bits = (uint32_t*)(base + 21406976); //  5,242,880 B
  double* gpart = (double*)(base + 26649856);    //      6,144 B (end 26,656,000)

  hipMemsetAsync(d_ws, 0, ZERO_BYTES, stream);

  prep<<<PREP_BLOCKS, 256, 0, stream>>>(cmv, cmc, v1, v2, W2, W2T, W1, W1L,
                                        input, XA, xcnt);
  h1_all<<<dim3(64, 4), 512, PANEL * 16, stream>>>(XA, W1L, b1, bits, v1, v2,
                                                   gpart);
  h2_all<<<BB / 2, 256, 0, stream>>>(bits, W2T, b2, gpart, xcnt, v1, v2,
                                     (float*)d_out);
}

// Round 6
// 285.764 us; speedup vs baseline: 1.3433x; 1.3433x over previous
//
#include <hip/hip_runtime.h>
#include <cstdint>
#include <cstddef>

// ---------------- problem constants (fixed by setup_inputs) ----------------
static constexpr int D_IN = 784;
static constexpr int H1   = 2048;
static constexpr int H2   = 10;
static constexpr int KK   = 10;
static constexpr int UU   = 2832;   // D_IN + H1
static constexpr int LL   = 128;
static constexpr int BB   = 1024;
static constexpr int TT   = 20;
static constexpr int HALF = BB * D_IN / 2;   // 401408 = 512*784
static constexpr int NCH  = 25;              // K chunks of 32 (784 -> 800 padded)
static constexpr int NLIMB = 3;              // signed base-256 limbs of round(W1*2^24)
static constexpr int XA_T  = 32 * NCH * 64;  // v4i per time-step of spike fragments
static constexpr int BITS_T = BB * 64;       // uint32 per time-step of h1s bitmask
static constexpr int PANEL = NCH * NLIMB * 64;  // v4i per ntile B-panel (4800)
static constexpr int NPART_GEN = 2000;       // gen_all partial slots
static constexpr int NPART_H1  = 256;        // h1_all partial slots
static constexpr int NPART = NPART_GEN + NPART_H1;

// setup mega-kernel block ranges (all atomic-free)
static constexpr int BLK_VALS  = UU / 4;                 // 708 (one wave per u)
static constexpr int BLK_W2T   = H1 / 256;               // 8
static constexpr int BLK_LIMBS = (64 * NCH * 64) / 256;  // 400
static constexpr int BLK_TRANS = D_IN * 4;               // 3136
static constexpr int SETUP_BLOCKS = BLK_VALS + BLK_W2T + BLK_LIMBS + BLK_TRANS;

typedef int v4i  __attribute__((ext_vector_type(4)));
typedef int v16i __attribute__((ext_vector_type(16)));

#define MFMA_I8 __builtin_amdgcn_mfma_i32_32x32x32_i8

// ---------------- JAX threefry2x32 (20 rounds), bit-exact ----------------
__device__ __forceinline__ uint32_t rotl32(uint32_t x, int d) {
  return (x << d) | (x >> (32 - d));
}
__device__ __forceinline__ void threefry2x32(uint32_t k0, uint32_t k1,
                                             uint32_t& x0, uint32_t& x1) {
  uint32_t ks2 = k0 ^ k1 ^ 0x1BD11BDAu;
  x0 += k0; x1 += k1;
#define TF_R(r) { x0 += x1; x1 = rotl32(x1, (r)); x1 ^= x0; }
  TF_R(13) TF_R(15) TF_R(26) TF_R(6)
  x0 += k1;  x1 += ks2 + 1u;
  TF_R(17) TF_R(29) TF_R(16) TF_R(24)
  x0 += ks2; x1 += k0 + 2u;
  TF_R(13) TF_R(15) TF_R(26) TF_R(6)
  x0 += k0;  x1 += k1 + 3u;
  TF_R(17) TF_R(29) TF_R(16) TF_R(24)
  x0 += k1;  x1 += ks2 + 4u;
  TF_R(13) TF_R(15) TF_R(26) TF_R(6)
  x0 += ks2; x1 += k0 + 5u;
#undef TF_R
}
__device__ __forceinline__ float bits_to_unif(uint32_t b) {
  uint32_t fb = (b >> 9) | 0x3F800000u;
  return __uint_as_float(fb) - 1.0f;
}

// ---------------- block-wide 3-way fp64 reduction -> per-block partial slot ----
__device__ __forceinline__ double wave_red(double v) {
  #pragma unroll
  for (int off = 32; off > 0; off >>= 1) v += __shfl_down(v, off, 64);
  return v;
}
__device__ __forceinline__ void block_store3(double s0, double s1, double s2,
                                             double* slot) {
  __shared__ double lds[3][8];
  int lane = threadIdx.x & 63, w = threadIdx.x >> 6;
  int nw = (int)(blockDim.x >> 6);
  s0 = wave_red(s0); s1 = wave_red(s1); s2 = wave_red(s2);
  if (lane == 0) { lds[0][w] = s0; lds[1][w] = s1; lds[2][w] = s2; }
  __syncthreads();
  if (threadIdx.x == 0) {
    double t0 = 0, t1 = 0, t2 = 0;
    for (int i = 0; i < nw; i++) { t0 += lds[0][i]; t1 += lds[1][i]; t2 += lds[2][i]; }
    slot[0] = t0; slot[1] = t1; slot[2] = t2;
  }
}

// ---------------- fused setup: vals + W2T + limbs + input transpose ------------
// ALL sections atomic-free and store-only -> no zeroed workspace, no memset.
__global__ __launch_bounds__(256)
void setup(const float* __restrict__ cmv, const int* __restrict__ cmc,
           float* __restrict__ v1, float* __restrict__ v2,
           const float* __restrict__ W2, float* __restrict__ W2T,
           const float* __restrict__ W1, v4i* __restrict__ W1L,
           const float* __restrict__ input, float* __restrict__ inT) {
  int bx = blockIdx.x;
  if (bx < BLK_VALS) {
    // ---- val1/val2: ONE WAVE PER u, serial over k (exact: small-int sums) ----
    int u = bx * 4 + (threadIdx.x >> 6);
    int lane = threadIdx.x & 63;
    float acc1 = 0.0f, acc2 = 0.0f;
    for (int k = 0; k < KK; k++) {
      const float* p = cmv + ((size_t)k * UU + u) * LL;
      float a = p[lane];
      float b = p[lane + 64];
      unsigned long long mlo = __ballot(a != 0.0f);
      unsigned long long mhi = __ballot(b != 0.0f);
      int c = cmc[k * UU + u];
      if (c > 0) {
        int last = mhi ? (127 - __builtin_clzll(mhi))
                       : (mlo ? (63 - __builtin_clzll(mlo)) : -1);
        if (last >= 0) acc1 += (float)(last - 1);
        acc2 += (float)c;
      }
    }
    if (lane == 0) { v1[u] = acc1; v2[u] = acc2; }
  } else if (bx < BLK_VALS + BLK_W2T) {
    // ---- W2T[i][j] = W2[j][i] ----
    int i = (bx - BLK_VALS) * 256 + threadIdx.x;
    #pragma unroll
    for (int j = 0; j < H2; j++) W2T[i * H2 + j] = W2[j * H1 + i];
  } else if (bx < BLK_VALS + BLK_W2T + BLK_LIMBS) {
    // ---- W1 -> 3 signed base-256 int8 limbs of round(W1*2^24), B-frag order ----
    // W1L index: ((ntile*NCH + chunk)*NLIMB + limb)*64 + lane
    // lane map: n = ntile*32 + (lane&31), k = chunk*32 + (lane>>5)*16 + j
    int tid = (bx - BLK_VALS - BLK_W2T) * 256 + threadIdx.x;
    int lane = tid & 63;
    int tc = tid >> 6;                           // ntile*NCH + chunk
    int n = ((tc / NCH) << 5) + (lane & 31);
    int chunk = tc % NCH;
    int k0 = chunk * 32 + (lane >> 5) * 16;
    union { v4i v; signed char b[16]; } d[NLIMB];
    #pragma unroll
    for (int j = 0; j < 16; j++) {
      long long F = 0;
      int k = k0 + j;
      if (k < D_IN) {
        double w = (double)W1[(size_t)n * D_IN + k];
        F = llround(w * 0x1p24);
        if (F >  8355711LL) F =  8355711LL;
        if (F < -8421504LL) F = -8421504LL;
      }
      #pragma unroll
      for (int l = 0; l < NLIMB; l++) {
        int dig = (int)((F + 128) & 255) - 128;
        d[l].b[j] = (signed char)dig;
        F = (F - dig) >> 8;
      }
    }
    #pragma unroll
    for (int l = 0; l < NLIMB; l++) W1L[(size_t)(tc * NLIMB + l) * 64 + lane] = d[l].v;
  } else {
    // ---- input transpose: inT[k*1024 + m] = input[m*784 + k] ----
    int b = bx - (BLK_VALS + BLK_W2T + BLK_LIMBS);
    int k = b >> 2;
    int m = ((b & 3) << 8) + threadIdx.x;
    inT[(size_t)k * BB + m] = input[(size_t)m * D_IN + k];
  }
}

// ---------------- spike generation (state-independent), A-fragment order -------
// XA_t entry index: (mtile*NCH + chunk)*64 + lane
// lane mapping: m = mtile*32 + (lane&31), k = chunk*32 + (lane>>5)*16 + j
__global__ __launch_bounds__(256)
void gen_all(const float* __restrict__ inT, v4i* __restrict__ XA,
             const float* __restrict__ v1, const float* __restrict__ v2,
             double* __restrict__ gpart) {
  int t  = blockIdx.x / 100;                     // 20 t x 100 blocks
  int gw = (blockIdx.x % 100) * 4 + (threadIdx.x >> 6);
  int lane = threadIdx.x & 63;
  int mtile = gw / NCH, chunk = gw - mtile * NCH;   // mtile in [0,16): m < 512
  int m = (mtile << 5) + (lane & 31);
  int k0 = chunk * 32 + (lane >> 5) * 16;
  uint32_t f0 = 0u, f1 = (uint32_t)t;
  threefry2x32(0u, 42u, f0, f1);
  union { v4i v; unsigned char b[16]; } r0, r1;
  double s0 = 0, s1 = 0, s2 = 0;
  v4i* XA_t = XA + (size_t)t * XA_T;
  if (k0 < D_IN) {   // whole 16-group valid (784 = 24*32+16: only chunk24/hi invalid)
    #pragma unroll
    for (int j = 0; j < 16; j++) {
      int k = k0 + j;
      uint32_t c0 = (uint32_t)(m * D_IN + k), c1 = c0 + (uint32_t)HALF;
      threefry2x32(f0, f1, c0, c1);
      float u0 = bits_to_unif(c0), u1 = bits_to_unif(c1);
      float i0 = inT[(size_t)k * BB + m];          // coalesced (lane-major m)
      float i1 = inT[(size_t)k * BB + m + 512];
      unsigned char x0 = (i0 > u0) ? 1 : 0;
      unsigned char x1 = (i1 > u1) ? 1 : 0;
      r0.b[j] = x0; r1.b[j] = x1;
      double xsum = (double)(x0 + x1);
      s0 += xsum * (double)v1[k];
      s1 += xsum * (double)v2[k];
      s2 += xsum;
    }
  } else {
    r0.v = (v4i){0, 0, 0, 0};
    r1.v = (v4i){0, 0, 0, 0};
  }
  XA_t[(size_t)(mtile * NCH + chunk) * 64 + lane] = r0.v;
  XA_t[(size_t)((mtile + 16) * NCH + chunk) * 64 + lane] = r1.v;   // m+512 partner
  block_store3(s0, s1, s2, gpart + 3 * (size_t)blockIdx.x);
}

// ---------------- h1: ALL 20 steps, membrane in regs, t-pair blocked -----------
// 512-thread blocks (8 waves = 2 waves/SIMD; LDS rounds to 128 KB so 1 block/CU
// — round-2 lesson; register tier ≥129 locks us at the 2-wave/SIMD tier).
// All 8 waves share ONE ntile B-panel in LDS (staged once, reused 20x); wave wv
// owns one mtile. XCD swizzle: dispatch id%8 = XCD, each XCD pinned to one
// mt-group so its L2 holds 1/4 of XA (round-4: FETCH 66->26 MB). K-loop fully
// unrolled. Chunk-0/1 B fragments are tp-INVARIANT -> hoisted to 24 persistent
// VGPRs (no LDS wait at K-pass start); next tp's chunk-0/1 A prefetched BEFORE
// the epilogue so HBM/L2 latency hides under the ~1200cy membrane/ballot work.
// setprio(1) over the MFMA-dense K-pass. Epilogue: exact int32 limb combine
// (mod-2^32 wraparound), f32 membrane chain.
__global__ __launch_bounds__(512, 2)
void h1_all(const v4i* __restrict__ XA, const v4i* __restrict__ W1L,
            const float* __restrict__ b1, uint32_t* __restrict__ bits,
            const float* __restrict__ v1, const float* __restrict__ v2,
            double* __restrict__ gpart) {
  extern __shared__ v4i bl[];                    // PANEL = 4800 v4i = 76800 B
  int lane = threadIdx.x & 63, wv = threadIdx.x >> 6;
  int id = blockIdx.x + (blockIdx.y << 6);       // dispatch-linear 0..255
  int xcd = id & 7;
  int idx = id >> 3;                             // 0..31
  int ntile = (idx << 1) | (xcd >> 2);           // 0..63
  int mtg = xcd & 3;                             // mt-group 0..3 (per-XCD fixed)
  int mt = mtg * 8 + wv;                         // [0,32)
  {
    const v4i* wp = W1L + (size_t)ntile * PANEL;
    for (int i = threadIdx.x; i < PANEL; i += 512) bl[i] = wp[i];
  }
  __syncthreads();

  int col = lane & 31;
  int gn = (ntile << 5) + col;
  float bias = b1[gn];
  double v1n = (double)v1[D_IN + gn], v2n = (double)v2[D_IN + gn];
  int scnt = 0;
  float mreg[16];
  #pragma unroll
  for (int r = 0; r < 16; r++) mreg[r] = 0.0f;

  const v4i* bq = bl + lane;
  // persistent chunk-0/1 B (tp-invariant, read from LDS exactly once)
  v4i B00 = bq[0],   B01 = bq[64],  B02 = bq[128];
  v4i B10 = bq[192], B11 = bq[256], B12 = bq[320];
  // A prefetch for tp=0 chunk 0/1
  const v4i* a0 = XA + (size_t)mt * (NCH * 64) + lane;
  const v4i* a1 = a0 + XA_T;
  v4i A00 = a0[0], A10 = a1[0], A01 = a0[64], A11 = a1[64];

  #pragma unroll 1
  for (int tp = 0; tp < TT / 2; tp++) {
    v16i c00 = {}, c01 = {}, c02 = {};           // t = 2tp,   limbs 0..2
    v16i c10 = {}, c11 = {}, c12 = {};           // t = 2tp+1, limbs 0..2
    __builtin_amdgcn_s_setprio(1);
    // chunk 0 (preloaded A + persistent B)
    c00 = MFMA_I8(A00, B00, c00, 0, 0, 0);
    c10 = MFMA_I8(A10, B00, c10, 0, 0, 0);
    c01 = MFMA_I8(A00, B01, c01, 0, 0, 0);
    c11 = MFMA_I8(A10, B01, c11, 0, 0, 0);
    c02 = MFMA_I8(A00, B02, c02, 0, 0, 0);
    c12 = MFMA_I8(A10, B02, c12, 0, 0, 0);
    // chunk 1
    c00 = MFMA_I8(A01, B10, c00, 0, 0, 0);
    c10 = MFMA_I8(A11, B10, c10, 0, 0, 0);
    c01 = MFMA_I8(A01, B11, c01, 0, 0, 0);
    c11 = MFMA_I8(A11, B11, c11, 0, 0, 0);
    c02 = MFMA_I8(A01, B12, c02, 0, 0, 0);
    c12 = MFMA_I8(A11, B12, c12, 0, 0, 0);
    // chunks 2..24, fully unrolled, direct indexing
    #pragma unroll
    for (int c = 2; c < NCH; c++) {
      v4i A0 = a0[c * 64], A1 = a1[c * 64];
      const v4i* br = bq + (size_t)c * (NLIMB * 64);
      v4i B0 = br[0], B1 = br[64], B2 = br[128];
      c00 = MFMA_I8(A0, B0, c00, 0, 0, 0);
      c10 = MFMA_I8(A1, B0, c10, 0, 0, 0);
      c01 = MFMA_I8(A0, B1, c01, 0, 0, 0);
      c11 = MFMA_I8(A1, B1, c11, 0, 0, 0);
      c02 = MFMA_I8(A0, B2, c02, 0, 0, 0);
      c12 = MFMA_I8(A1, B2, c12, 0, 0, 0);
    }
    __builtin_amdgcn_s_setprio(0);
    // cross-tp prefetch: next K-pass's chunk-0/1 A issued under the epilogue
    {
      const v4i* a0n = a0 + ((tp + 1 < TT / 2) ? 2 * XA_T : 0);
      const v4i* a1n = a0n + XA_T;
      A00 = a0n[0]; A10 = a1n[0]; A01 = a0n[64]; A11 = a1n[64];
      a0 = a0n; a1 = a1n;
    }
    // epilogue: t = 2tp then 2tp+1 (membrane chain order preserved)
    // C/D layout (32x32): col=lane&31, row=(r&3)+8*(r>>2)+4*(lane>>5)
    #pragma unroll
    for (int half = 0; half < 2; half++) {
      const v16i& q0 = half ? c10 : c00;
      const v16i& q1 = half ? c11 : c01;
      const v16i& q2 = half ? c12 : c02;
      uint32_t* btm = bits + (size_t)(2 * tp + half) * BITS_T
                    + ((size_t)mt << 5) * 64 + ntile;
      #pragma unroll
      for (int r = 0; r < 16; r++) {
        // exact: true val fits int31, so mod-2^32 wraparound combine is exact
        int val = (int)((uint32_t)q0[r] + ((uint32_t)q1[r] << 8)
                        + ((uint32_t)q2[r] << 16));
        float dot = (float)val * 0x1p-24f + bias;
        float mp = mreg[r];
        float mnew = (mp > 0.5f) ? dot : fmaf(mp, 0.2f, dot);
        bool s = (mnew > 0.5f);
        mreg[r] = mnew;
        unsigned long long bm = __ballot(s);
        int rowA = (r & 3) + 8 * (r >> 2);
        if ((lane & 31) == 0)
          btm[(size_t)(rowA + ((lane >> 5) << 2)) * 64] = (uint32_t)(bm >> (lane & 32));
        scnt += s ? 1 : 0;
      }
    }
  }
  double sc = (double)scnt;
  block_store3(sc * v1n, sc * v2n, sc, gpart + 3 * (size_t)(NPART_GEN + id));
}

// ---------------- h2: ALL 20 steps, W2 slices in registers, 2 rows/block -------
// block = 4 waves; wave wq covers n in [wq*512,(wq+1)*512) for both rows
// (8 n-words per lane, weights register-resident); cross-wave combine via LDS;
// waves 0,1 advance the h2 chain for rows b0+0, b0+1 in lanes 0..9.
// Block 0 additionally reduces the 2256 partial triples -> out[BB*H2 + 0..2].
__global__ __launch_bounds__(256)
void h2_all(const uint32_t* __restrict__ bits, const float* __restrict__ W2T,
            const float* __restrict__ b2, const double* __restrict__ gpart,
            float* __restrict__ out) {
  int lane = threadIdx.x & 63, wq = threadIdx.x >> 6;
  int b0 = blockIdx.x * 2;
  float w[8][10];
  #pragma unroll
  for (int c = 0; c < 8; c++) {
    int n = (wq << 9) + (c << 6) + lane;         // n = wq*512 + c*64 + lane
    #pragma unroll
    for (int j = 0; j < 10; j++) w[c][j] = W2T[(size_t)n * H2 + j];
  }
  float m = 0.0f, sp = 0.0f, sm = 0.0f;
  float b2v = (lane < 10) ? b2[lane] : 0.0f;
  __shared__ float part[4][2][10];               // [wq][row][j]
  #pragma unroll 1
  for (int t = 0; t < TT; t++) {
    const uint32_t* bt = bits + (size_t)t * BITS_T;
    #pragma unroll
    for (int r = 0; r < 2; r++) {
      // lane L holds mask word (wq*16 + (L&15)) of row b0+r
      uint32_t myw = bt[(size_t)(b0 + r) * 64 + (wq << 4) + (lane & 15)];
      float p[10];
      #pragma unroll
      for (int j = 0; j < 10; j++) p[j] = 0.0f;
      #pragma unroll
      for (int c = 0; c < 8; c++) {
        // word for n = wq*512+c*64+lane lives at source lane 2c+(lane>>5)
        uint32_t wd = __shfl(myw, (c << 1) + (lane >> 5), 64);
        float f = (float)((wd >> (lane & 31)) & 1u);
        #pragma unroll
        for (int j = 0; j < 10; j++) p[j] += f * w[c][j];
      }
      #pragma unroll
      for (int j = 0; j < 10; j++) {
        float v = p[j];
        #pragma unroll
        for (int off = 32; off > 0; off >>= 1) v += __shfl_xor(v, off, 64);
        p[j] = v;
      }
      if (lane == 0) {
        #pragma unroll
        for (int j = 0; j < 10; j++) part[wq][r][j] = p[j];
      }
    }
    __syncthreads();
    if (wq < 2 && lane < 10) {
      float red = part[0][wq][lane] + part[1][wq][lane]
                + part[2][wq][lane] + part[3][wq][lane];
      m = m * 0.2f * (1.0f - sp) + red + b2v;
      sp = (m > 0.5f) ? 1.0f : 0.0f;
      sm += sp;
    }
    __syncthreads();
  }
  if (wq < 2 && lane < 10)
    out[(size_t)(b0 + wq) * H2 + lane] = (float)((double)sm / (double)TT);

  if (blockIdx.x == 0) {
    // final reduction of the per-block partials (no atomics anywhere)
    double t0 = 0, t1 = 0, t2 = 0;
    for (int i = threadIdx.x; i < NPART; i += 256) {
      t0 += gpart[3 * (size_t)i];
      t1 += gpart[3 * (size_t)i + 1];
      t2 += gpart[3 * (size_t)i + 2];
    }
    __shared__ double fin[3][4];
    t0 = wave_red(t0); t1 = wave_red(t1); t2 = wave_red(t2);
    if (lane == 0) { fin[0][wq] = t0; fin[1][wq] = t1; fin[2][wq] = t2; }
    __syncthreads();
    if (threadIdx.x == 0) {
      double a = 0, b = 0, cc = 0;
      #pragma unroll
      for (int i = 0; i < 4; i++) { a += fin[0][i]; b += fin[1][i]; cc += fin[2][i]; }
      out[(size_t)BB * H2 + 0] = (float)a;
      out[(size_t)BB * H2 + 1] = (float)b;
      out[(size_t)BB * H2 + 2] = (float)cc;
    }
  }
}

// ---------------- launch (4 dispatches, NO memset — nothing needs zeroing) -----
extern "C" void kernel_launch(void* const* d_in, const int* in_sizes, int n_in,
                              void* d_out, int out_size, void* d_ws, size_t ws_size,
                              hipStream_t stream) {
  (void)in_sizes; (void)n_in; (void)out_size; (void)ws_size;
  const float* input = (const float*)d_in[0];
  const float* W1    = (const float*)d_in[1];
  const float* b1    = (const float*)d_in[2];
  const float* W2    = (const float*)d_in[3];
  const float* b2    = (const float*)d_in[4];
  const float* cmv   = (const float*)d_in[5];
  const int*   cmc   = (const int*)d_in[6];

  char* base = (char*)d_ws;
  // every buffer fully written before read — no zeroed region
  float*  v1   = (float*)(base + 0);             //     11,328 B
  float*  v2   = (float*)(base + 11328);         //     11,328 B
  float*  W2T  = (float*)(base + 22656);         //     81,920 B
  v4i*    W1L  = (v4i*)(base + 104576);          //  4,915,200 B
  v4i*    XA   = (v4i*)(base + 5019776);         // 16,384,000 B
  uint32_t* bits = (uint32_t*)(base + 21403776); //  5,242,880 B
  float*  inT  = (float*)(base + 26646656);      //  3,211,264 B
  double* gpart = (double*)(base + 29857920);    //     54,144 B (end 29,912,064)

  setup<<<SETUP_BLOCKS, 256, 0, stream>>>(cmv, cmc, v1, v2, W2, W2T, W1, W1L,
                                          input, inT);
  gen_all<<<TT * 100, 256, 0, stream>>>(inT, XA, v1, v2, gpart);
  h1_all<<<dim3(64, 4), 512, PANEL * 16, stream>>>(XA, W1L, b1, bits, v1, v2,
                                                   gpart);
  h2_all<<<BB / 2, 256, 0, stream>>>(bits, W2T, b2, gpart, (float*)d_out);
}